// Round 14
// baseline (429.409 us; speedup 1.0000x reference)
//
#include <hip/hip_runtime.h>

typedef unsigned short u16;
typedef unsigned int u32;
typedef __bf16 bf16x8 __attribute__((ext_vector_type(8)));
typedef float fx4 __attribute__((ext_vector_type(4)));

__device__ __forceinline__ float bf2f(u16 u) {
    return __uint_as_float(((u32)u) << 16);
}
__device__ __forceinline__ u16 f2bf(float f) {
    u32 x = __float_as_uint(f);
    u32 r = (x + 0x7fffu + ((x >> 16) & 1u)) >> 16;
    return (u16)r;
}

// async global->LDS, 16B per lane (gfx950). LDS dest must be linear:
// wave-uniform base + lane*16 (we pass per-lane ptrs equal to that).
__device__ __forceinline__ void gld16(const u16* g, u16* l) {
    __builtin_amdgcn_global_load_lds(
        (const __attribute__((address_space(1))) void*)g,
        (__attribute__((address_space(3))) void*)l, 16, 0, 0);
}

#define MFMA16(a, b, c) __builtin_amdgcn_mfma_f32_16x16x32_bf16((a), (b), (c), 0, 0, 0)

// ---------------------------------------------------------------------------
// fp32 -> bf16 bulk convert: x (8388608) | wqkv_w (12582912) | out_w (4194304)
// grid 12288 x 256, 8 elems/thread. Segment boundaries are block-aligned.
// ---------------------------------------------------------------------------
__global__ __launch_bounds__(256) void cvt_kernel(const float* __restrict__ x,
                                                  const float* __restrict__ w1,
                                                  const float* __restrict__ w2,
                                                  u16* __restrict__ xb,
                                                  u16* __restrict__ w1b,
                                                  u16* __restrict__ w2b) {
    size_t g = ((size_t)blockIdx.x * 256 + threadIdx.x) * 8;
    const float* src;
    u16* dst;
    if (g < 8388608) {
        src = x;
        dst = xb;
    } else if (g < 20971520) {
        src = w1 - 8388608;
        dst = w1b - 8388608;
    } else {
        src = w2 - 20971520;
        dst = w2b - 20971520;
    }
    float4 a = *(const float4*)&src[g];
    float4 b = *(const float4*)&src[g + 4];
    u16 v[8];
    v[0] = f2bf(a.x);
    v[1] = f2bf(a.y);
    v[2] = f2bf(a.z);
    v[3] = f2bf(a.w);
    v[4] = f2bf(b.x);
    v[5] = f2bf(b.y);
    v[6] = f2bf(b.z);
    v[7] = f2bf(b.w);
    *(uint4*)&dst[g] = *(const uint4*)v;
}

// ---------------------------------------------------------------------------
// GEMM (m97 structure + counted-vmcnt dbuf): C = A * B^T + bias.
// 128x128 tile, BK=32, global_load_lds width 16.
// R14 changes (counters: VGPR=56, Occupancy 33% = 2.7 blocks/CU):
//  (a) __launch_bounds__(256,4): min 4 blocks/CU (VGPR cap 128 >> 56 used,
//      LDS 32K allows 5) -> more TLP to hide the barrier drain.
//  (b) chunked XCD swizzle (T1): l' = (l&7)*nwg/8 + l>>3 (nwg%8==0 for both
//      launches) -> each XCD runs 4 consecutive M-rows across all N;
//      A-row panel (2 MB) stays L2-resident per XCD.
// MODE 0: write fp32 Cf[M][N]. MODE 1: qkv scatter (bf16) to qb/kb/vb.
// ---------------------------------------------------------------------------
template <int MODE>
__global__ __launch_bounds__(256, 4) void gemm_bt(const u16* __restrict__ A,
                                                  const u16* __restrict__ B,
                                                  const float* __restrict__ bias,
                                                  float* __restrict__ Cf,
                                                  u16* __restrict__ qb,
                                                  u16* __restrict__ kb,
                                                  u16* __restrict__ vb,
                                                  int N, int K) {
    __shared__ __align__(16) u16 As[2][128 * 32];
    __shared__ __align__(16) u16 Bs[2][128 * 32];

    const int tid = threadIdx.x;
    const int lane = tid & 63;
    const int wave = tid >> 6;
    const int quad = lane >> 4;
    const int m16 = lane & 15;
    const int wm = wave >> 1, wn = wave & 1;

    // bijective chunked XCD swizzle (nwg % 8 == 0 in both launches)
    const int nwg = gridDim.x * gridDim.y;
    const int l = blockIdx.y * gridDim.x + blockIdx.x;
    const int l2 = (l & 7) * (nwg >> 3) + (l >> 3);
    const int bm = (l2 / gridDim.x) * 128;
    const int bn = (l2 % gridDim.x) * 128;

    const int r0 = tid >> 2;
    const int u0 = (tid & 3) ^ ((r0 >> 1) & 3);
    const int r1 = (tid + 256) >> 2;
    const int u1 = ((tid + 256) & 3) ^ ((r1 >> 1) & 3);
    const u16* a0 = &A[(size_t)(bm + r0) * K + u0 * 8];
    const u16* a1 = &A[(size_t)(bm + r1) * K + u1 * 8];
    const u16* b0 = &B[(size_t)(bn + r0) * K + u0 * 8];
    const u16* b1 = &B[(size_t)(bn + r1) * K + u1 * 8];

    const int su = (quad ^ ((m16 >> 1) & 3)) * 8;

#define GLDT(kt_, buf_)                                                       \
    {                                                                         \
        const int k0_ = (kt_) << 5;                                           \
        gld16(a0 + k0_, &As[buf_][tid * 8]);                                  \
        gld16(a1 + k0_, &As[buf_][(tid + 256) * 8]);                          \
        gld16(b0 + k0_, &Bs[buf_][tid * 8]);                                  \
        gld16(b1 + k0_, &Bs[buf_][(tid + 256) * 8]);                          \
    }

    const fx4 zero4 = {0.f, 0.f, 0.f, 0.f};
    fx4 acc[4][4];
#pragma unroll
    for (int i = 0; i < 4; ++i)
#pragma unroll
        for (int j = 0; j < 4; ++j) acc[i][j] = zero4;

    const int nk = K >> 5;
    GLDT(0, 0);
    if (nk > 1) {
        GLDT(1, 1);
        asm volatile("s_waitcnt vmcnt(4)" ::: "memory");
    } else {
        asm volatile("s_waitcnt vmcnt(0)" ::: "memory");
    }
    __builtin_amdgcn_s_barrier();

    int cur = 0;
    for (int kt = 0; kt < nk; ++kt) {
        bf16x8 af[4], bfr[4];
#pragma unroll
        for (int t = 0; t < 4; ++t) {
            af[t] = *(const bf16x8*)&As[cur][(wm * 64 + t * 16 + m16) * 32 + su];
            bfr[t] = *(const bf16x8*)&Bs[cur][(wn * 64 + t * 16 + m16) * 32 + su];
        }
        __builtin_amdgcn_s_setprio(1);
#pragma unroll
        for (int mt = 0; mt < 4; ++mt)
#pragma unroll
            for (int nt = 0; nt < 4; ++nt)
                acc[mt][nt] = MFMA16(af[mt], bfr[nt], acc[mt][nt]);
        __builtin_amdgcn_s_setprio(0);
        __builtin_amdgcn_sched_barrier(0);
        asm volatile("s_waitcnt lgkmcnt(0)" ::: "memory");
        __builtin_amdgcn_s_barrier();

        if (kt + 2 < nk) {
            GLDT(kt + 2, cur);
            asm volatile("s_waitcnt vmcnt(4)" ::: "memory");
        } else {
            asm volatile("s_waitcnt vmcnt(0)" ::: "memory");
        }
        __builtin_amdgcn_s_barrier();
        cur ^= 1;
    }

#pragma unroll
    for (int mt = 0; mt < 4; ++mt) {
#pragma unroll
        for (int r = 0; r < 4; ++r) {
            int row = bm + wm * 64 + mt * 16 + quad * 4 + r;
#pragma unroll
            for (int nt = 0; nt < 4; ++nt) {
                int col = bn + wn * 64 + nt * 16 + m16;
                float v = acc[mt][nt][r] + bias[col];
                if (MODE == 0) {
                    Cf[(size_t)row * N + col] = v;
                } else {
                    int which = col >> 11;
                    int h = (col >> 7) & 15;
                    int d = col & 127;
                    int b = row >> 11;
                    int s = row & 2047;
                    u16* dst = (which == 0) ? qb : ((which == 1) ? kb : vb);
                    dst[(size_t)((b * 16 + h) * 2048 + s) * 128 + d] = f2bf(v);
                }
            }
        }
    }
#undef GLDT
}

// ---------------------------------------------------------------------------
// RoPE in place on q and k (bf16), layout [bh][s][128]; pair (i, i+64).
// ---------------------------------------------------------------------------
__global__ __launch_bounds__(256) void rope_kernel(u16* __restrict__ q,
                                                   u16* __restrict__ k) {
    int t = blockIdx.x * 256 + threadIdx.x;
    int i = t & 63;
    int s = (t >> 6) & 2047;
    int bh = t >> 17;
    float inv = exp2f(-(float)i * 0.2076205059304595f);  // 10000^(-i/64)
    float ang = (float)s * inv;
    float sn, cs;
    sincosf(ang, &sn, &cs);
    size_t base = ((size_t)bh * 2048 + s) * 128 + i;
    {
        float x1 = bf2f(q[base]), x2 = bf2f(q[base + 64]);
        q[base] = f2bf(x1 * cs - x2 * sn);
        q[base + 64] = f2bf(x1 * sn + x2 * cs);
    }
    {
        float x1 = bf2f(k[base]), x2 = bf2f(k[base + 64]);
        k[base] = f2bf(x1 * cs - x2 * sn);
        k[base + 64] = f2bf(x1 * sn + x2 * cs);
    }
}

// ---------------------------------------------------------------------------
// V transpose: [bh][s][d] -> [bh][d][s] (bf16 ws).
// ---------------------------------------------------------------------------
__global__ __launch_bounds__(256) void vtrans_kernel(const u16* __restrict__ v,
                                                     u16* __restrict__ vt) {
    __shared__ __align__(16) u16 L[128 * 66];
    const int tid = threadIdx.x;
    const int kb = blockIdx.x * 64;
    const int bh = blockIdx.y;
    const u16* vp = v + (size_t)bh * 2048 * 128;
    u16* op = vt + (size_t)bh * 128 * 2048;
#pragma unroll
    for (int i = 0; i < 4; ++i) {
        int c = i * 256 + tid;
        int t = c >> 4, d8 = (c & 15) << 3;
        uint4 x = *(const uint4*)&vp[(kb + t) * 128 + d8];
        const u16* xs = (const u16*)&x;
#pragma unroll
        for (int j = 0; j < 8; ++j) L[(d8 + j) * 66 + t] = xs[j];
    }
    __syncthreads();
#pragma unroll
    for (int i = 0; i < 4; ++i) {
        int c = i * 256 + tid;
        int d = c >> 3, t8 = (c & 7) << 3;
        uint4 x;
        u16* xs = (u16*)&x;
#pragma unroll
        for (int j = 0; j < 8; ++j) xs[j] = L[d * 66 + t8 + j];
        *(uint4*)&op[(size_t)d * 2048 + kb + t8] = x;
    }
}

// ---------------------------------------------------------------------------
// Flash attention (causal), 512 threads = 8 waves, FULL 128-row Q-tile.
// (Unchanged from R13 — validated: dropped out of top-5.)
// Each wave owns 16 q-rows (1 frag). Block processes Q-tiles qt0 and
// 15-qt0 as two sequential passes over the same bh K/V stream:
// staged K-tiles = 34 exactly -> equal work, placement-independent.
// Grid 256 = 8 pairs x 32 bh. LDS 80 KiB -> 2 blocks/CU.
// ---------------------------------------------------------------------------
__global__ __launch_bounds__(512, 2) void attn_kernel(const u16* __restrict__ q,
                                                      const u16* __restrict__ k,
                                                      const u16* __restrict__ vt,
                                                      u16* __restrict__ ctx) {
    __shared__ __align__(16) u16 Ks[2][64 * 128];   // K [token][d], src-swz
    __shared__ __align__(16) u16 Vs[2][128 * 64];   // V^T [d][token], src-swz
    __shared__ __align__(16) u16 Ps[8][16 * 64];    // per-wave P, swizzled

    const int tid = threadIdx.x;
    const int lane = tid & 63;
    const int wave = tid >> 6;
    const int quad = lane >> 4;
    const int m16 = lane & 15;

    const int l = blockIdx.x;
    const int qt0 = l & 7;
    const int bh = l >> 3;
    const int b = bh >> 4, h = bh & 15;
    const u16* qp = q + (size_t)bh * 2048 * 128;
    const u16* kp = k + (size_t)bh * 2048 * 128;
    const u16* vp = vt + (size_t)bh * 128 * 2048;
    const float scale = 0.08838834764831845f;  // 1/sqrt(128)
    const fx4 zero4 = {0.f, 0.f, 0.f, 0.f};

    // staging geometry: 2 K-slots + 2 V-slots per thread per tile.
    int ksrc[2], vsrc[2];
#pragma unroll
    for (int i = 0; i < 2; ++i) {
        int s = tid + i * 512;
        int r = s >> 4, p = s & 15;
        ksrc[i] = r * 128 + (p ^ (r & 7)) * 8;
        int d = s >> 3, pv = s & 7;
        vsrc[i] = d * 2048 + (pv ^ (d & 7)) * 8;
    }

#define GLD_TILE(kb_, buf_)                                                   \
    {                                                                         \
        _Pragma("unroll") for (int ii = 0; ii < 2; ++ii) {                    \
            gld16(kp + (size_t)(kb_)*128 + ksrc[ii],                          \
                  &Ks[buf_][tid * 8 + ii * 4096]);                            \
            gld16(vp + (kb_) + vsrc[ii], &Vs[buf_][tid * 8 + ii * 4096]);     \
        }                                                                     \
    }

#pragma unroll 1
    for (int pass = 0; pass < 2; ++pass) {
        const int qt = pass ? (15 - qt0) : qt0;
        const int qrow0 = qt * 128 + wave * 16;  // wave's 16 rows
        const int nkt = 2 * qt + 2;

        // Q fragment (A-layout: row=m16, k=c*32+quad*8+j)
        bf16x8 qf[4];
#pragma unroll
        for (int c = 0; c < 4; ++c)
            qf[c] = *(const bf16x8*)&qp[(size_t)(qrow0 + m16) * 128 + c * 32 +
                                        quad * 8];

        fx4 o[8];
#pragma unroll
        for (int dn = 0; dn < 8; ++dn) o[dn] = zero4;
        float mi[4], li[4];
#pragma unroll
        for (int r = 0; r < 4; ++r) {
            mi[r] = -1e30f;
            li[r] = 0.f;
        }

        GLD_TILE(0, 0);
        __syncthreads();  // tile 0 resident
        int cur = 0;
        for (int kt = 0; kt < nkt; ++kt) {
            const int kb = kt * 64;
            // prefetch tile kt+1 into the idle buffer (flies under compute)
            if (kt + 1 < nkt) GLD_TILE(kb + 64, cur ^ 1);

            // QK^T: 16 rows x 64 cols
            fx4 sc[4];
#pragma unroll
            for (int nt = 0; nt < 4; ++nt) sc[nt] = zero4;
            __builtin_amdgcn_s_setprio(1);
#pragma unroll
            for (int c = 0; c < 4; ++c)
#pragma unroll
                for (int nt = 0; nt < 4; ++nt) {
                    int e = (nt * 16 + m16) * 128 + c * 32 + quad * 8;
                    bf16x8 kf =
                        *(const bf16x8*)&Ks[cur][e ^ ((m16 & 7) << 3)];
                    sc[nt] = MFMA16(qf[c], kf, sc[nt]);
                }
            __builtin_amdgcn_s_setprio(0);

            // shuffle online softmax (row = quad*4+r, its 16 cols on lanes
            // quad*16..quad*16+15; xor 1/2/4/8 stays inside the group)
#pragma unroll
            for (int r = 0; r < 4; ++r) {
                int rg = qrow0 + quad * 4 + r;
                float mx = mi[r];
#pragma unroll
                for (int nt = 0; nt < 4; ++nt) {
                    int cg = kb + nt * 16 + m16;
                    float s = sc[nt][r] * scale;
                    s = (cg <= rg) ? s : -1e30f;
                    sc[nt][r] = s;
                    mx = fmaxf(mx, s);
                }
                mx = fmaxf(mx, __shfl_xor(mx, 1));
                mx = fmaxf(mx, __shfl_xor(mx, 2));
                mx = fmaxf(mx, __shfl_xor(mx, 4));
                mx = fmaxf(mx, __shfl_xor(mx, 8));
                float alpha = __expf(mi[r] - mx);
                mi[r] = mx;
                float rsum = 0.f;
                int row = quad * 4 + r;
#pragma unroll
                for (int nt = 0; nt < 4; ++nt) {
                    float p = __expf(sc[nt][r] - mx);
                    Ps[wave][(row * 64 + nt * 16 + m16) ^ ((row & 7) << 3)] =
                        f2bf(p);
                    rsum += p;
                }
                rsum += __shfl_xor(rsum, 1);
                rsum += __shfl_xor(rsum, 2);
                rsum += __shfl_xor(rsum, 4);
                rsum += __shfl_xor(rsum, 8);
                li[r] = li[r] * alpha + rsum;
#pragma unroll
                for (int dn = 0; dn < 8; ++dn) o[dn][r] *= alpha;
            }

            // O += P * V. Ps wave-private: same-wave ds ordering suffices.
            __builtin_amdgcn_s_setprio(1);
#pragma unroll
            for (int c2 = 0; c2 < 2; ++c2) {
                bf16x8 pf = *(const bf16x8*)&Ps[wave][(m16 * 64 + c2 * 32 +
                                                       quad * 8) ^
                                                      ((m16 & 7) << 3)];
#pragma unroll
                for (int dn = 0; dn < 8; ++dn) {
                    int e = (dn * 16 + m16) * 64 + c2 * 32 + quad * 8;
                    bf16x8 vf =
                        *(const bf16x8*)&Vs[cur][e ^ ((m16 & 7) << 3)];
                    o[dn] = MFMA16(pf, vf, o[dn]);
                }
            }
            __builtin_amdgcn_s_setprio(0);

            __syncthreads();  // drains prefetch; ends reads of buf cur
            cur ^= 1;
        }

        // epilogue for this pass's 16 rows
#pragma unroll
        for (int r = 0; r < 4; ++r) {
            int row = qrow0 + quad * 4 + r;
            float inv = 1.0f / li[r];
#pragma unroll
            for (int dn = 0; dn < 8; ++dn) {
                int d = dn * 16 + m16;
                ctx[((size_t)(b * 2048 + row)) * 2048 + h * 128 + d] =
                    f2bf(o[dn][r] * inv);
            }
        }
    }
}

// ---------------------------------------------------------------------------
// ws (64 MiB u16): xb 8388608 | wqkvb 12582912 | v/ctx 8388608 | outwb 4194304
// d_out (32 MiB used as scratch until final GEMM): q 8388608 | k 8388608
// vt reuses xb after the QKV GEMM. Final GEMM overwrites d_out (q,k dead).
// ---------------------------------------------------------------------------
extern "C" void kernel_launch(void* const* d_in, const int* in_sizes, int n_in,
                              void* d_out, int out_size, void* d_ws,
                              size_t ws_size, hipStream_t stream) {
    const float* x = (const float*)d_in[0];
    const float* wqkv_w = (const float*)d_in[1];
    const float* wqkv_b = (const float*)d_in[2];
    const float* out_w = (const float*)d_in[3];
    const float* out_b = (const float*)d_in[4];
    u16* ws = (u16*)d_ws;

    u16* xb = ws;                   // 8388608 u16 (later: vt)
    u16* wqkvb = ws + 8388608;      // 12582912 u16
    u16* vb = ws + 20971520;        // 8388608 u16 (later: ctx)
    u16* outwb = ws + 29360128;     // 4194304 u16
    u16* vtb = xb;
    u16* ctx = vb;
    u16* qb = (u16*)d_out;          // 8388608 u16
    u16* kb = qb + 8388608;         // 8388608 u16

    cvt_kernel<<<12288, 256, 0, stream>>>(x, wqkv_w, out_w, xb, wqkvb, outwb);
    gemm_bt<1><<<dim3(48, 32), 256, 0, stream>>>(xb, wqkvb, wqkv_b, nullptr,
                                                 qb, kb, vb, 6144, 2048);
    rope_kernel<<<16384, 256, 0, stream>>>(qb, kb);
    vtrans_kernel<<<dim3(32, 32), 256, 0, stream>>>(vb, vtb);
    attn_kernel<<<256, 512, 0, stream>>>(qb, kb, vtb, ctx);
    gemm_bt<0><<<dim3(16, 32), 256, 0, stream>>>(ctx, outwb, out_b,
                                                 (float*)d_out, nullptr,
                                                 nullptr, nullptr, 2048, 2048);
}

// Round 15
// 426.701 us; speedup vs baseline: 1.0063x; 1.0063x over previous
//
#include <hip/hip_runtime.h>

typedef unsigned short u16;
typedef unsigned int u32;
typedef __bf16 bf16x8 __attribute__((ext_vector_type(8)));
typedef float fx4 __attribute__((ext_vector_type(4)));

__device__ __forceinline__ float bf2f(u16 u) {
    return __uint_as_float(((u32)u) << 16);
}
__device__ __forceinline__ u16 f2bf(float f) {
    u32 x = __float_as_uint(f);
    u32 r = (x + 0x7fffu + ((x >> 16) & 1u)) >> 16;
    return (u16)r;
}

// async global->LDS, 16B per lane (gfx950). LDS dest must be linear:
// wave-uniform base + lane*16 (we pass per-lane ptrs equal to that).
__device__ __forceinline__ void gld16(const u16* g, u16* l) {
    __builtin_amdgcn_global_load_lds(
        (const __attribute__((address_space(1))) void*)g,
        (__attribute__((address_space(3))) void*)l, 16, 0, 0);
}

#define MFMA16(a, b, c) __builtin_amdgcn_mfma_f32_16x16x32_bf16((a), (b), (c), 0, 0, 0)

// ---------------------------------------------------------------------------
// fp32 -> bf16 bulk convert: x (8388608) | wqkv_w (12582912) | out_w (4194304)
// ---------------------------------------------------------------------------
__global__ __launch_bounds__(256) void cvt_kernel(const float* __restrict__ x,
                                                  const float* __restrict__ w1,
                                                  const float* __restrict__ w2,
                                                  u16* __restrict__ xb,
                                                  u16* __restrict__ w1b,
                                                  u16* __restrict__ w2b) {
    size_t g = ((size_t)blockIdx.x * 256 + threadIdx.x) * 8;
    const float* src;
    u16* dst;
    if (g < 8388608) {
        src = x;
        dst = xb;
    } else if (g < 20971520) {
        src = w1 - 8388608;
        dst = w1b - 8388608;
    } else {
        src = w2 - 20971520;
        dst = w2b - 20971520;
    }
    float4 a = *(const float4*)&src[g];
    float4 b = *(const float4*)&src[g + 4];
    u16 v[8];
    v[0] = f2bf(a.x);
    v[1] = f2bf(a.y);
    v[2] = f2bf(a.z);
    v[3] = f2bf(a.w);
    v[4] = f2bf(b.x);
    v[5] = f2bf(b.y);
    v[6] = f2bf(b.z);
    v[7] = f2bf(b.w);
    *(uint4*)&dst[g] = *(const uint4*)v;
}

// ---------------------------------------------------------------------------
// QKV GEMM — phase-pipelined, counted-vmcnt, never-drain (T3+T4 derived).
// BM=256 x BN=128, BK=64, 512 thr = 8 waves (wm=wave>>1 in 0..3, wn=wave&1).
// Per-wave output 64x64 = acc[4][4]. K-tile split into 2 phases (k-halves
// of 32 = exactly one MFMA-K). Per phase:
//   8 ds_read_b128 -> issue 3 gld16 (tile t+1, same half, buf^1)
//   -> lgkmcnt(0)+sched_barrier -> setprio(1) 16 MFMA setprio(0)
//   -> s_waitcnt vmcnt(3) -> s_barrier.
// Ledger (FIFO, 3 loads/phase/thread): phase-end vmcnt(3) retires exactly
// the half needed by the NEXT phase; prologue stages t0(k0,k1), vmcnt(3)
// leaves k1 in flight. vmcnt never 0 in the loop. Buffer safety: phase
// (t,h) writes buf^1 half h whose reads ended at tile t-1 phase h's
// barrier (2 barriers prior).
// LDS: As[2][2][256*32] 64K + Bs[2][2][128*32] 32K = 96 KiB -> 1 block/CU.
// Staging slots row-major (64B-coalesced) with unit XOR (s&3)^(row&3);
// reads XOR the same involution (<=4-way conflicts).
// Grid 768 = 16 Mtiles x 48 Ntiles = 3 exact dispatch rounds (no tail).
// Epilogue: qkv scatter (bf16) with bias to qb/kb/vb.
// ---------------------------------------------------------------------------
__global__ __launch_bounds__(512, 2) void gemm_qkv(const u16* __restrict__ A,
                                                   const u16* __restrict__ B,
                                                   const float* __restrict__ bias,
                                                   u16* __restrict__ qb,
                                                   u16* __restrict__ kb,
                                                   u16* __restrict__ vb) {
    const int K = 2048;
    __shared__ __align__(16) u16 As[2][2][256 * 32];
    __shared__ __align__(16) u16 Bs[2][2][128 * 32];

    const int tid = threadIdx.x;
    const int lane = tid & 63;
    const int wave = tid >> 6;
    const int quad = lane >> 4;
    const int m16 = lane & 15;
    const int wm = wave >> 1;  // 0..3
    const int wn = wave & 1;   // 0..1

    const int bm = (blockIdx.x / 48) * 256;
    const int bn = (blockIdx.x % 48) * 128;
    const u16* Ab = A + (size_t)bm * K;
    const u16* Bbp = B + (size_t)bn * K;

    // staging: A half = 256x32 = 1024 slots (thread: tid, tid+512);
    //          B half = 128x32 = 512 slots (thread: tid).
    // slot s: row = s>>2, phys unit = s&3 holds global unit (s&3)^(row&3).
    const int arow0 = tid >> 2, au0 = (tid & 3) ^ (arow0 & 3);
    const int arow1 = (tid + 512) >> 2, au1 = ((tid + 512) & 3) ^ (arow1 & 3);
    const int brow = tid >> 2, bu = (tid & 3) ^ (brow & 3);

#define QISSUE(t_, h_, buf_)                                                  \
    {                                                                         \
        const int ko_ = (t_)*64 + (h_)*32;                                    \
        gld16(Ab + (size_t)arow0 * K + ko_ + au0 * 8,                         \
              &As[buf_][h_][tid * 8]);                                        \
        gld16(Ab + (size_t)arow1 * K + ko_ + au1 * 8,                         \
              &As[buf_][h_][(tid + 512) * 8]);                                \
        gld16(Bbp + (size_t)brow * K + ko_ + bu * 8,                          \
              &Bs[buf_][h_][tid * 8]);                                        \
    }

    const fx4 zero4 = {0.f, 0.f, 0.f, 0.f};
    fx4 acc[4][4];
#pragma unroll
    for (int i = 0; i < 4; ++i)
#pragma unroll
        for (int j = 0; j < 4; ++j) acc[i][j] = zero4;

#define QPHASE(t_, h_, b_)                                                    \
    {                                                                         \
        bf16x8 af[4], bfr[4];                                                 \
        _Pragma("unroll") for (int mt = 0; mt < 4; ++mt) {                    \
            int row = wm * 64 + mt * 16 + m16;                                \
            af[mt] = *(const bf16x8*)&As[b_][h_]                              \
                         [row * 32 + ((quad ^ (row & 3)) << 3)];              \
        }                                                                     \
        _Pragma("unroll") for (int nt = 0; nt < 4; ++nt) {                    \
            int rc = wn * 64 + nt * 16 + m16;                                 \
            bfr[nt] = *(const bf16x8*)&Bs[b_][h_]                             \
                          [rc * 32 + ((quad ^ (rc & 3)) << 3)];               \
        }                                                                     \
        if ((t_) + 1 < 32) QISSUE((t_) + 1, h_, (b_) ^ 1);                    \
        asm volatile("s_waitcnt lgkmcnt(0)" ::: "memory");                    \
        __builtin_amdgcn_sched_barrier(0);                                    \
        __builtin_amdgcn_s_setprio(1);                                        \
        _Pragma("unroll") for (int mt = 0; mt < 4; ++mt)                      \
            _Pragma("unroll") for (int nt = 0; nt < 4; ++nt)                  \
                acc[mt][nt] = MFMA16(af[mt], bfr[nt], acc[mt][nt]);           \
        __builtin_amdgcn_s_setprio(0);                                       \
        __builtin_amdgcn_sched_barrier(0);                                    \
        asm volatile("s_waitcnt vmcnt(3)" ::: "memory");                      \
        __builtin_amdgcn_s_barrier();                                         \
    }

    // prologue: stage tile 0 (both halves); k0 resident, k1 in flight.
    QISSUE(0, 0, 0);
    QISSUE(0, 1, 0);
    asm volatile("s_waitcnt vmcnt(3)" ::: "memory");
    __builtin_amdgcn_s_barrier();

    for (int t = 0; t < 32; ++t) {
        const int b = t & 1;
        QPHASE(t, 0, b);
        QPHASE(t, 1, b);
    }

    // epilogue: qkv scatter
#pragma unroll
    for (int mt = 0; mt < 4; ++mt) {
#pragma unroll
        for (int rr = 0; rr < 4; ++rr) {
            int row = bm + wm * 64 + mt * 16 + quad * 4 + rr;
#pragma unroll
            for (int nt = 0; nt < 4; ++nt) {
                int col = bn + wn * 64 + nt * 16 + m16;
                float v = acc[mt][nt][rr] + bias[col];
                int which = col >> 11;
                int h = (col >> 7) & 15;
                int d = col & 127;
                int b2 = row >> 11;
                int s = row & 2047;
                u16* dst = (which == 0) ? qb : ((which == 1) ? kb : vb);
                dst[(size_t)((b2 * 16 + h) * 2048 + s) * 128 + d] = f2bf(v);
            }
        }
    }
#undef QPHASE
#undef QISSUE
}

// ---------------------------------------------------------------------------
// GEMM (m97 structure + counted-vmcnt dbuf): C = A * B^T + bias, fp32 out.
// 128x128 tile, BK=32. R13 version verbatim (R14's launch-bounds hint and
// XCD swizzle were null/harmful - reverted). Used for output projection.
// ---------------------------------------------------------------------------
template <int MODE>
__global__ __launch_bounds__(256, 2) void gemm_bt(const u16* __restrict__ A,
                                                  const u16* __restrict__ B,
                                                  const float* __restrict__ bias,
                                                  float* __restrict__ Cf,
                                                  u16* __restrict__ qb,
                                                  u16* __restrict__ kb,
                                                  u16* __restrict__ vb,
                                                  int N, int K) {
    __shared__ __align__(16) u16 As[2][128 * 32];
    __shared__ __align__(16) u16 Bs[2][128 * 32];

    const int tid = threadIdx.x;
    const int lane = tid & 63;
    const int wave = tid >> 6;
    const int quad = lane >> 4;
    const int m16 = lane & 15;
    const int wm = wave >> 1, wn = wave & 1;
    const int bm = blockIdx.y * 128, bn = blockIdx.x * 128;

    const int r0 = tid >> 2;
    const int u0 = (tid & 3) ^ ((r0 >> 1) & 3);
    const int r1 = (tid + 256) >> 2;
    const int u1 = ((tid + 256) & 3) ^ ((r1 >> 1) & 3);
    const u16* a0 = &A[(size_t)(bm + r0) * K + u0 * 8];
    const u16* a1 = &A[(size_t)(bm + r1) * K + u1 * 8];
    const u16* b0 = &B[(size_t)(bn + r0) * K + u0 * 8];
    const u16* b1 = &B[(size_t)(bn + r1) * K + u1 * 8];

    const int su = (quad ^ ((m16 >> 1) & 3)) * 8;

#define GLDT(kt_, buf_)                                                       \
    {                                                                         \
        const int k0_ = (kt_) << 5;                                           \
        gld16(a0 + k0_, &As[buf_][tid * 8]);                                  \
        gld16(a1 + k0_, &As[buf_][(tid + 256) * 8]);                          \
        gld16(b0 + k0_, &Bs[buf_][tid * 8]);                                  \
        gld16(b1 + k0_, &Bs[buf_][(tid + 256) * 8]);                          \
    }

    const fx4 zero4 = {0.f, 0.f, 0.f, 0.f};
    fx4 acc[4][4];
#pragma unroll
    for (int i = 0; i < 4; ++i)
#pragma unroll
        for (int j = 0; j < 4; ++j) acc[i][j] = zero4;

    const int nk = K >> 5;
    GLDT(0, 0);
    if (nk > 1) {
        GLDT(1, 1);
        asm volatile("s_waitcnt vmcnt(4)" ::: "memory");
    } else {
        asm volatile("s_waitcnt vmcnt(0)" ::: "memory");
    }
    __builtin_amdgcn_s_barrier();

    int cur = 0;
    for (int kt = 0; kt < nk; ++kt) {
        bf16x8 af[4], bfr[4];
#pragma unroll
        for (int t = 0; t < 4; ++t) {
            af[t] = *(const bf16x8*)&As[cur][(wm * 64 + t * 16 + m16) * 32 + su];
            bfr[t] = *(const bf16x8*)&Bs[cur][(wn * 64 + t * 16 + m16) * 32 + su];
        }
        __builtin_amdgcn_s_setprio(1);
#pragma unroll
        for (int mt = 0; mt < 4; ++mt)
#pragma unroll
            for (int nt = 0; nt < 4; ++nt)
                acc[mt][nt] = MFMA16(af[mt], bfr[nt], acc[mt][nt]);
        __builtin_amdgcn_s_setprio(0);
        __builtin_amdgcn_sched_barrier(0);
        asm volatile("s_waitcnt lgkmcnt(0)" ::: "memory");
        __builtin_amdgcn_s_barrier();

        if (kt + 2 < nk) {
            GLDT(kt + 2, cur);
            asm volatile("s_waitcnt vmcnt(4)" ::: "memory");
        } else {
            asm volatile("s_waitcnt vmcnt(0)" ::: "memory");
        }
        __builtin_amdgcn_s_barrier();
        cur ^= 1;
    }

#pragma unroll
    for (int mt = 0; mt < 4; ++mt) {
#pragma unroll
        for (int r = 0; r < 4; ++r) {
            int row = bm + wm * 64 + mt * 16 + quad * 4 + r;
#pragma unroll
            for (int nt = 0; nt < 4; ++nt) {
                int col = bn + wn * 64 + nt * 16 + m16;
                float v = acc[mt][nt][r] + bias[col];
                if (MODE == 0) {
                    Cf[(size_t)row * N + col] = v;
                } else {
                    int which = col >> 11;
                    int h = (col >> 7) & 15;
                    int d = col & 127;
                    int b = row >> 11;
                    int s = row & 2047;
                    u16* dst = (which == 0) ? qb : ((which == 1) ? kb : vb);
                    dst[(size_t)((b * 16 + h) * 2048 + s) * 128 + d] = f2bf(v);
                }
            }
        }
    }
#undef GLDT
}

// ---------------------------------------------------------------------------
// RoPE in place on q and k (bf16), layout [bh][s][128]; pair (i, i+64).
// ---------------------------------------------------------------------------
__global__ __launch_bounds__(256) void rope_kernel(u16* __restrict__ q,
                                                   u16* __restrict__ k) {
    int t = blockIdx.x * 256 + threadIdx.x;
    int i = t & 63;
    int s = (t >> 6) & 2047;
    int bh = t >> 17;
    float inv = exp2f(-(float)i * 0.2076205059304595f);  // 10000^(-i/64)
    float ang = (float)s * inv;
    float sn, cs;
    sincosf(ang, &sn, &cs);
    size_t base = ((size_t)bh * 2048 + s) * 128 + i;
    {
        float x1 = bf2f(q[base]), x2 = bf2f(q[base + 64]);
        q[base] = f2bf(x1 * cs - x2 * sn);
        q[base + 64] = f2bf(x1 * sn + x2 * cs);
    }
    {
        float x1 = bf2f(k[base]), x2 = bf2f(k[base + 64]);
        k[base] = f2bf(x1 * cs - x2 * sn);
        k[base + 64] = f2bf(x1 * sn + x2 * cs);
    }
}

// ---------------------------------------------------------------------------
// V transpose: [bh][s][d] -> [bh][d][s] (bf16 ws).
// ---------------------------------------------------------------------------
__global__ __launch_bounds__(256) void vtrans_kernel(const u16* __restrict__ v,
                                                     u16* __restrict__ vt) {
    __shared__ __align__(16) u16 L[128 * 66];
    const int tid = threadIdx.x;
    const int kb = blockIdx.x * 64;
    const int bh = blockIdx.y;
    const u16* vp = v + (size_t)bh * 2048 * 128;
    u16* op = vt + (size_t)bh * 128 * 2048;
#pragma unroll
    for (int i = 0; i < 4; ++i) {
        int c = i * 256 + tid;
        int t = c >> 4, d8 = (c & 15) << 3;
        uint4 x = *(const uint4*)&vp[(kb + t) * 128 + d8];
        const u16* xs = (const u16*)&x;
#pragma unroll
        for (int j = 0; j < 8; ++j) L[(d8 + j) * 66 + t] = xs[j];
    }
    __syncthreads();
#pragma unroll
    for (int i = 0; i < 4; ++i) {
        int c = i * 256 + tid;
        int d = c >> 3, t8 = (c & 7) << 3;
        uint4 x;
        u16* xs = (u16*)&x;
#pragma unroll
        for (int j = 0; j < 8; ++j) xs[j] = L[d * 66 + t8 + j];
        *(uint4*)&op[(size_t)d * 2048 + kb + t8] = x;
    }
}

// ---------------------------------------------------------------------------
// Flash attention (causal), 512 threads = 8 waves, FULL 128-row Q-tile.
// (Unchanged from R13 — validated.)
// ---------------------------------------------------------------------------
__global__ __launch_bounds__(512, 2) void attn_kernel(const u16* __restrict__ q,
                                                      const u16* __restrict__ k,
                                                      const u16* __restrict__ vt,
                                                      u16* __restrict__ ctx) {
    __shared__ __align__(16) u16 Ks[2][64 * 128];   // K [token][d], src-swz
    __shared__ __align__(16) u16 Vs[2][128 * 64];   // V^T [d][token], src-swz
    __shared__ __align__(16) u16 Ps[8][16 * 64];    // per-wave P, swizzled

    const int tid = threadIdx.x;
    const int lane = tid & 63;
    const int wave = tid >> 6;
    const int quad = lane >> 4;
    const int m16 = lane & 15;

    const int l = blockIdx.x;
    const int qt0 = l & 7;
    const int bh = l >> 3;
    const int b = bh >> 4, h = bh & 15;
    const u16* qp = q + (size_t)bh * 2048 * 128;
    const u16* kp = k + (size_t)bh * 2048 * 128;
    const u16* vp = vt + (size_t)bh * 128 * 2048;
    const float scale = 0.08838834764831845f;  // 1/sqrt(128)
    const fx4 zero4 = {0.f, 0.f, 0.f, 0.f};

    // staging geometry: 2 K-slots + 2 V-slots per thread per tile.
    int ksrc[2], vsrc[2];
#pragma unroll
    for (int i = 0; i < 2; ++i) {
        int s = tid + i * 512;
        int r = s >> 4, p = s & 15;
        ksrc[i] = r * 128 + (p ^ (r & 7)) * 8;
        int d = s >> 3, pv = s & 7;
        vsrc[i] = d * 2048 + (pv ^ (d & 7)) * 8;
    }

#define GLD_TILE(kb_, buf_)                                                   \
    {                                                                         \
        _Pragma("unroll") for (int ii = 0; ii < 2; ++ii) {                    \
            gld16(kp + (size_t)(kb_)*128 + ksrc[ii],                          \
                  &Ks[buf_][tid * 8 + ii * 4096]);                            \
            gld16(vp + (kb_) + vsrc[ii], &Vs[buf_][tid * 8 + ii * 4096]);     \
        }                                                                     \
    }

#pragma unroll 1
    for (int pass = 0; pass < 2; ++pass) {
        const int qt = pass ? (15 - qt0) : qt0;
        const int qrow0 = qt * 128 + wave * 16;  // wave's 16 rows
        const int nkt = 2 * qt + 2;

        // Q fragment (A-layout: row=m16, k=c*32+quad*8+j)
        bf16x8 qf[4];
#pragma unroll
        for (int c = 0; c < 4; ++c)
            qf[c] = *(const bf16x8*)&qp[(size_t)(qrow0 + m16) * 128 + c * 32 +
                                        quad * 8];

        fx4 o[8];
#pragma unroll
        for (int dn = 0; dn < 8; ++dn) o[dn] = zero4;
        float mi[4], li[4];
#pragma unroll
        for (int r = 0; r < 4; ++r) {
            mi[r] = -1e30f;
            li[r] = 0.f;
        }

        GLD_TILE(0, 0);
        __syncthreads();  // tile 0 resident
        int cur = 0;
        for (int kt = 0; kt < nkt; ++kt) {
            const int kb = kt * 64;
            // prefetch tile kt+1 into the idle buffer (flies under compute)
            if (kt + 1 < nkt) GLD_TILE(kb + 64, cur ^ 1);

            // QK^T: 16 rows x 64 cols
            fx4 sc[4];
#pragma unroll
            for (int nt = 0; nt < 4; ++nt) sc[nt] = zero4;
            __builtin_amdgcn_s_setprio(1);
#pragma unroll
            for (int c = 0; c < 4; ++c)
#pragma unroll
                for (int nt = 0; nt < 4; ++nt) {
                    int e = (nt * 16 + m16) * 128 + c * 32 + quad * 8;
                    bf16x8 kf =
                        *(const bf16x8*)&Ks[cur][e ^ ((m16 & 7) << 3)];
                    sc[nt] = MFMA16(qf[c], kf, sc[nt]);
                }
            __builtin_amdgcn_s_setprio(0);

            // shuffle online softmax (row = quad*4+r, its 16 cols on lanes
            // quad*16..quad*16+15; xor 1/2/4/8 stays inside the group)
#pragma unroll
            for (int r = 0; r < 4; ++r) {
                int rg = qrow0 + quad * 4 + r;
                float mx = mi[r];
#pragma unroll
                for (int nt = 0; nt < 4; ++nt) {
                    int cg = kb + nt * 16 + m16;
                    float s = sc[nt][r] * scale;
                    s = (cg <= rg) ? s : -1e30f;
                    sc[nt][r] = s;
                    mx = fmaxf(mx, s);
                }
                mx = fmaxf(mx, __shfl_xor(mx, 1));
                mx = fmaxf(mx, __shfl_xor(mx, 2));
                mx = fmaxf(mx, __shfl_xor(mx, 4));
                mx = fmaxf(mx, __shfl_xor(mx, 8));
                float alpha = __expf(mi[r] - mx);
                mi[r] = mx;
                float rsum = 0.f;
                int row = quad * 4 + r;
#pragma unroll
                for (int nt = 0; nt < 4; ++nt) {
                    float p = __expf(sc[nt][r] - mx);
                    Ps[wave][(row * 64 + nt * 16 + m16) ^ ((row & 7) << 3)] =
                        f2bf(p);
                    rsum += p;
                }
                rsum += __shfl_xor(rsum, 1);
                rsum += __shfl_xor(rsum, 2);
                rsum += __shfl_xor(rsum, 4);
                rsum += __shfl_xor(rsum, 8);
                li[r] = li[r] * alpha + rsum;
#pragma unroll
                for (int dn = 0; dn < 8; ++dn) o[dn][r] *= alpha;
            }

            // O += P * V. Ps wave-private: same-wave ds ordering suffices.
            __builtin_amdgcn_s_setprio(1);
#pragma unroll
            for (int c2 = 0; c2 < 2; ++c2) {
                bf16x8 pf = *(const bf16x8*)&Ps[wave][(m16 * 64 + c2 * 32 +
                                                       quad * 8) ^
                                                      ((m16 & 7) << 3)];
#pragma unroll
                for (int dn = 0; dn < 8; ++dn) {
                    int e = (dn * 16 + m16) * 64 + c2 * 32 + quad * 8;
                    bf16x8 vf =
                        *(const bf16x8*)&Vs[cur][e ^ ((m16 & 7) << 3)];
                    o[dn] = MFMA16(pf, vf, o[dn]);
                }
            }
            __builtin_amdgcn_s_setprio(0);

            __syncthreads();  // drains prefetch; ends reads of buf cur
            cur ^= 1;
        }

        // epilogue for this pass's 16 rows
#pragma unroll
        for (int r = 0; r < 4; ++r) {
            int row = qrow0 + quad * 4 + r;
            float inv = 1.0f / li[r];
#pragma unroll
            for (int dn = 0; dn < 8; ++dn) {
                int d = dn * 16 + m16;
                ctx[((size_t)(b * 2048 + row)) * 2048 + h * 128 + d] =
                    f2bf(o[dn][r] * inv);
            }
        }
    }
}

// ---------------------------------------------------------------------------
// ws (64 MiB u16): xb 8388608 | wqkvb 12582912 | v/ctx 8388608 | outwb 4194304
// d_out (32 MiB used as scratch until final GEMM): q 8388608 | k 8388608
// vt reuses xb after the QKV GEMM. Final GEMM overwrites d_out (q,k dead).
// ---------------------------------------------------------------------------
extern "C" void kernel_launch(void* const* d_in, const int* in_sizes, int n_in,
                              void* d_out, int out_size, void* d_ws,
                              size_t ws_size, hipStream_t stream) {
    const float* x = (const float*)d_in[0];
    const float* wqkv_w = (const float*)d_in[1];
    const float* wqkv_b = (const float*)d_in[2];
    const float* out_w = (const float*)d_in[3];
    const float* out_b = (const float*)d_in[4];
    u16* ws = (u16*)d_ws;

    u16* xb = ws;                   // 8388608 u16 (later: vt)
    u16* wqkvb = ws + 8388608;      // 12582912 u16
    u16* vb = ws + 20971520;        // 8388608 u16 (later: ctx)
    u16* outwb = ws + 29360128;     // 4194304 u16
    u16* vtb = xb;
    u16* ctx = vb;
    u16* qb = (u16*)d_out;          // 8388608 u16
    u16* kb = qb + 8388608;         // 8388608 u16

    cvt_kernel<<<12288, 256, 0, stream>>>(x, wqkv_w, out_w, xb, wqkvb, outwb);
    gemm_qkv<<<768, 512, 0, stream>>>(xb, wqkvb, wqkv_b, qb, kb, vb);
    rope_kernel<<<16384, 256, 0, stream>>>(qb, kb);
    vtrans_kernel<<<dim3(32, 32), 256, 0, stream>>>(vb, vtb);
    attn_kernel<<<256, 512, 0, stream>>>(qb, kb, vtb, ctx);
    gemm_bt<0><<<dim3(16, 32), 256, 0, stream>>>(ctx, outwb, out_b,
                                                 (float*)d_out, nullptr,
                                                 nullptr, nullptr, 2048, 2048);
}

// Round 16
// 419.143 us; speedup vs baseline: 1.0245x; 1.0180x over previous
//
#include <hip/hip_runtime.h>

typedef unsigned short u16;
typedef unsigned int u32;
typedef __bf16 bf16x8 __attribute__((ext_vector_type(8)));
typedef float fx4 __attribute__((ext_vector_type(4)));

__device__ __forceinline__ float bf2f(u16 u) {
    return __uint_as_float(((u32)u) << 16);
}
__device__ __forceinline__ u16 f2bf(float f) {
    u32 x = __float_as_uint(f);
    u32 r = (x + 0x7fffu + ((x >> 16) & 1u)) >> 16;
    return (u16)r;
}

// async global->LDS, 16B per lane (gfx950). LDS dest must be linear:
// wave-uniform base + lane*16 (we pass per-lane ptrs equal to that).
__device__ __forceinline__ void gld16(const u16* g, u16* l) {
    __builtin_amdgcn_global_load_lds(
        (const __attribute__((address_space(1))) void*)g,
        (__attribute__((address_space(3))) void*)l, 16, 0, 0);
}

#define MFMA16(a, b, c) __builtin_amdgcn_mfma_f32_16x16x32_bf16((a), (b), (c), 0, 0, 0)

// ---------------------------------------------------------------------------
// fp32 -> bf16 bulk convert: x (8388608) | wqkv_w (12582912) | out_w (4194304)
// ---------------------------------------------------------------------------
__global__ __launch_bounds__(256) void cvt_kernel(const float* __restrict__ x,
                                                  const float* __restrict__ w1,
                                                  const float* __restrict__ w2,
                                                  u16* __restrict__ xb,
                                                  u16* __restrict__ w1b,
                                                  u16* __restrict__ w2b) {
    size_t g = ((size_t)blockIdx.x * 256 + threadIdx.x) * 8;
    const float* src;
    u16* dst;
    if (g < 8388608) {
        src = x;
        dst = xb;
    } else if (g < 20971520) {
        src = w1 - 8388608;
        dst = w1b - 8388608;
    } else {
        src = w2 - 20971520;
        dst = w2b - 20971520;
    }
    float4 a = *(const float4*)&src[g];
    float4 b = *(const float4*)&src[g + 4];
    u16 v[8];
    v[0] = f2bf(a.x);
    v[1] = f2bf(a.y);
    v[2] = f2bf(a.z);
    v[3] = f2bf(a.w);
    v[4] = f2bf(b.x);
    v[5] = f2bf(b.y);
    v[6] = f2bf(b.z);
    v[7] = f2bf(b.w);
    *(uint4*)&dst[g] = *(const uint4*)v;
}

// ---------------------------------------------------------------------------
// QKV GEMM — phase-pipelined, counted-vmcnt, never-drain (T3+T4).
// BM=256 x BN=128, BK=64, 512 thr = 8 waves. Per-wave output 64x64.
// R16 fix: swizzle XOR uses ((row>>1)&3), not (row&3). Bank base =
// 16*(row&1) + 4*u mod 32: with u = quad^(row&3), lanes {0,4,8,12} all hit
// bank 0 (4-way, the 12.6M conflicts); with u = quad^((row>>1)&3) the worst
// case is 2-way (free, matches old gemm_bt's measured 0). Same involution
// applied to the staging SOURCE unit (rule #21: both-sides-or-neither).
// Per phase: 8 ds_read_b128 -> issue 3 gld16 (t+1, same half, buf^1)
//   -> lgkmcnt(0)+sched_barrier -> setprio(1) 16 MFMA setprio(0)
//   -> s_waitcnt vmcnt(3) -> s_barrier.  vmcnt never 0 in the loop.
// LDS 96 KiB -> 1 block/CU. Grid 768 = 16x48 (3 exact rounds).
// ---------------------------------------------------------------------------
__global__ __launch_bounds__(512, 2) void gemm_qkv(const u16* __restrict__ A,
                                                   const u16* __restrict__ B,
                                                   const float* __restrict__ bias,
                                                   u16* __restrict__ qb,
                                                   u16* __restrict__ kb,
                                                   u16* __restrict__ vb) {
    const int K = 2048;
    __shared__ __align__(16) u16 As[2][2][256 * 32];
    __shared__ __align__(16) u16 Bs[2][2][128 * 32];

    const int tid = threadIdx.x;
    const int lane = tid & 63;
    const int wave = tid >> 6;
    const int quad = lane >> 4;
    const int m16 = lane & 15;
    const int wm = wave >> 1;  // 0..3
    const int wn = wave & 1;   // 0..1

    const int bm = (blockIdx.x / 48) * 256;
    const int bn = (blockIdx.x % 48) * 128;
    const u16* Ab = A + (size_t)bm * K;
    const u16* Bbp = B + (size_t)bn * K;

    // staging: A half = 256x32 = 1024 slots (thread: tid, tid+512);
    //          B half = 128x32 = 512 slots (thread: tid).
    // slot s: row = s>>2, phys unit p = s&3 holds global unit p^((row>>1)&3).
    const int arow0 = tid >> 2, au0 = (tid & 3) ^ ((arow0 >> 1) & 3);
    const int arow1 = (tid + 512) >> 2, au1 = ((tid + 512) & 3) ^ ((arow1 >> 1) & 3);
    const int brow = tid >> 2, bu = (tid & 3) ^ ((brow >> 1) & 3);

#define QISSUE(t_, h_, buf_)                                                  \
    {                                                                         \
        const int ko_ = (t_)*64 + (h_)*32;                                    \
        gld16(Ab + (size_t)arow0 * K + ko_ + au0 * 8,                         \
              &As[buf_][h_][tid * 8]);                                        \
        gld16(Ab + (size_t)arow1 * K + ko_ + au1 * 8,                         \
              &As[buf_][h_][(tid + 512) * 8]);                                \
        gld16(Bbp + (size_t)brow * K + ko_ + bu * 8,                          \
              &Bs[buf_][h_][tid * 8]);                                        \
    }

    const fx4 zero4 = {0.f, 0.f, 0.f, 0.f};
    fx4 acc[4][4];
#pragma unroll
    for (int i = 0; i < 4; ++i)
#pragma unroll
        for (int j = 0; j < 4; ++j) acc[i][j] = zero4;

#define QPHASE(t_, h_, b_)                                                    \
    {                                                                         \
        bf16x8 af[4], bfr[4];                                                 \
        _Pragma("unroll") for (int mt = 0; mt < 4; ++mt) {                    \
            int row = wm * 64 + mt * 16 + m16;                                \
            af[mt] = *(const bf16x8*)&As[b_][h_]                              \
                         [row * 32 + ((quad ^ ((row >> 1) & 3)) << 3)];       \
        }                                                                     \
        _Pragma("unroll") for (int nt = 0; nt < 4; ++nt) {                    \
            int rc = wn * 64 + nt * 16 + m16;                                 \
            bfr[nt] = *(const bf16x8*)&Bs[b_][h_]                             \
                          [rc * 32 + ((quad ^ ((rc >> 1) & 3)) << 3)];        \
        }                                                                     \
        if ((t_) + 1 < 32) QISSUE((t_) + 1, h_, (b_) ^ 1);                    \
        asm volatile("s_waitcnt lgkmcnt(0)" ::: "memory");                    \
        __builtin_amdgcn_sched_barrier(0);                                    \
        __builtin_amdgcn_s_setprio(1);                                        \
        _Pragma("unroll") for (int mt = 0; mt < 4; ++mt)                      \
            _Pragma("unroll") for (int nt = 0; nt < 4; ++nt)                  \
                acc[mt][nt] = MFMA16(af[mt], bfr[nt], acc[mt][nt]);           \
        __builtin_amdgcn_s_setprio(0);                                       \
        __builtin_amdgcn_sched_barrier(0);                                    \
        asm volatile("s_waitcnt vmcnt(3)" ::: "memory");                      \
        __builtin_amdgcn_s_barrier();                                         \
    }

    // prologue: stage tile 0 (both halves); k0 resident, k1 in flight.
    QISSUE(0, 0, 0);
    QISSUE(0, 1, 0);
    asm volatile("s_waitcnt vmcnt(3)" ::: "memory");
    __builtin_amdgcn_s_barrier();

    for (int t = 0; t < 32; ++t) {
        const int b = t & 1;
        QPHASE(t, 0, b);
        QPHASE(t, 1, b);
    }

    // epilogue: qkv scatter
#pragma unroll
    for (int mt = 0; mt < 4; ++mt) {
#pragma unroll
        for (int rr = 0; rr < 4; ++rr) {
            int row = bm + wm * 64 + mt * 16 + quad * 4 + rr;
#pragma unroll
            for (int nt = 0; nt < 4; ++nt) {
                int col = bn + wn * 64 + nt * 16 + m16;
                float v = acc[mt][nt][rr] + bias[col];
                int which = col >> 11;
                int h = (col >> 7) & 15;
                int d = col & 127;
                int b2 = row >> 11;
                int s = row & 2047;
                u16* dst = (which == 0) ? qb : ((which == 1) ? kb : vb);
                dst[(size_t)((b2 * 16 + h) * 2048 + s) * 128 + d] = f2bf(v);
            }
        }
    }
#undef QPHASE
#undef QISSUE
}

// ---------------------------------------------------------------------------
// GEMM (m97 structure + counted-vmcnt dbuf): C = A * B^T + bias, fp32 out.
// 128x128 tile, BK=32. R13 version verbatim. Used for output projection.
// ---------------------------------------------------------------------------
template <int MODE>
__global__ __launch_bounds__(256, 2) void gemm_bt(const u16* __restrict__ A,
                                                  const u16* __restrict__ B,
                                                  const float* __restrict__ bias,
                                                  float* __restrict__ Cf,
                                                  u16* __restrict__ qb,
                                                  u16* __restrict__ kb,
                                                  u16* __restrict__ vb,
                                                  int N, int K) {
    __shared__ __align__(16) u16 As[2][128 * 32];
    __shared__ __align__(16) u16 Bs[2][128 * 32];

    const int tid = threadIdx.x;
    const int lane = tid & 63;
    const int wave = tid >> 6;
    const int quad = lane >> 4;
    const int m16 = lane & 15;
    const int wm = wave >> 1, wn = wave & 1;
    const int bm = blockIdx.y * 128, bn = blockIdx.x * 128;

    const int r0 = tid >> 2;
    const int u0 = (tid & 3) ^ ((r0 >> 1) & 3);
    const int r1 = (tid + 256) >> 2;
    const int u1 = ((tid + 256) & 3) ^ ((r1 >> 1) & 3);
    const u16* a0 = &A[(size_t)(bm + r0) * K + u0 * 8];
    const u16* a1 = &A[(size_t)(bm + r1) * K + u1 * 8];
    const u16* b0 = &B[(size_t)(bn + r0) * K + u0 * 8];
    const u16* b1 = &B[(size_t)(bn + r1) * K + u1 * 8];

    const int su = (quad ^ ((m16 >> 1) & 3)) * 8;

#define GLDT(kt_, buf_)                                                       \
    {                                                                         \
        const int k0_ = (kt_) << 5;                                           \
        gld16(a0 + k0_, &As[buf_][tid * 8]);                                  \
        gld16(a1 + k0_, &As[buf_][(tid + 256) * 8]);                          \
        gld16(b0 + k0_, &Bs[buf_][tid * 8]);                                  \
        gld16(b1 + k0_, &Bs[buf_][(tid + 256) * 8]);                          \
    }

    const fx4 zero4 = {0.f, 0.f, 0.f, 0.f};
    fx4 acc[4][4];
#pragma unroll
    for (int i = 0; i < 4; ++i)
#pragma unroll
        for (int j = 0; j < 4; ++j) acc[i][j] = zero4;

    const int nk = K >> 5;
    GLDT(0, 0);
    if (nk > 1) {
        GLDT(1, 1);
        asm volatile("s_waitcnt vmcnt(4)" ::: "memory");
    } else {
        asm volatile("s_waitcnt vmcnt(0)" ::: "memory");
    }
    __builtin_amdgcn_s_barrier();

    int cur = 0;
    for (int kt = 0; kt < nk; ++kt) {
        bf16x8 af[4], bfr[4];
#pragma unroll
        for (int t = 0; t < 4; ++t) {
            af[t] = *(const bf16x8*)&As[cur][(wm * 64 + t * 16 + m16) * 32 + su];
            bfr[t] = *(const bf16x8*)&Bs[cur][(wn * 64 + t * 16 + m16) * 32 + su];
        }
        __builtin_amdgcn_s_setprio(1);
#pragma unroll
        for (int mt = 0; mt < 4; ++mt)
#pragma unroll
            for (int nt = 0; nt < 4; ++nt)
                acc[mt][nt] = MFMA16(af[mt], bfr[nt], acc[mt][nt]);
        __builtin_amdgcn_s_setprio(0);
        __builtin_amdgcn_sched_barrier(0);
        asm volatile("s_waitcnt lgkmcnt(0)" ::: "memory");
        __builtin_amdgcn_s_barrier();

        if (kt + 2 < nk) {
            GLDT(kt + 2, cur);
            asm volatile("s_waitcnt vmcnt(4)" ::: "memory");
        } else {
            asm volatile("s_waitcnt vmcnt(0)" ::: "memory");
        }
        __builtin_amdgcn_s_barrier();
        cur ^= 1;
    }

#pragma unroll
    for (int mt = 0; mt < 4; ++mt) {
#pragma unroll
        for (int r = 0; r < 4; ++r) {
            int row = bm + wm * 64 + mt * 16 + quad * 4 + r;
#pragma unroll
            for (int nt = 0; nt < 4; ++nt) {
                int col = bn + wn * 64 + nt * 16 + m16;
                float v = acc[mt][nt][r] + bias[col];
                if (MODE == 0) {
                    Cf[(size_t)row * N + col] = v;
                } else {
                    int which = col >> 11;
                    int h = (col >> 7) & 15;
                    int d = col & 127;
                    int b = row >> 11;
                    int s = row & 2047;
                    u16* dst = (which == 0) ? qb : ((which == 1) ? kb : vb);
                    dst[(size_t)((b * 16 + h) * 2048 + s) * 128 + d] = f2bf(v);
                }
            }
        }
    }
#undef GLDT
}

// ---------------------------------------------------------------------------
// RoPE in place on q and k (bf16), layout [bh][s][128]; pair (i, i+64).
// ---------------------------------------------------------------------------
__global__ __launch_bounds__(256) void rope_kernel(u16* __restrict__ q,
                                                   u16* __restrict__ k) {
    int t = blockIdx.x * 256 + threadIdx.x;
    int i = t & 63;
    int s = (t >> 6) & 2047;
    int bh = t >> 17;
    float inv = exp2f(-(float)i * 0.2076205059304595f);  // 10000^(-i/64)
    float ang = (float)s * inv;
    float sn, cs;
    sincosf(ang, &sn, &cs);
    size_t base = ((size_t)bh * 2048 + s) * 128 + i;
    {
        float x1 = bf2f(q[base]), x2 = bf2f(q[base + 64]);
        q[base] = f2bf(x1 * cs - x2 * sn);
        q[base + 64] = f2bf(x1 * sn + x2 * cs);
    }
    {
        float x1 = bf2f(k[base]), x2 = bf2f(k[base + 64]);
        k[base] = f2bf(x1 * cs - x2 * sn);
        k[base + 64] = f2bf(x1 * sn + x2 * cs);
    }
}

// ---------------------------------------------------------------------------
// V transpose: [bh][s][d] -> [bh][d][s] (bf16 ws).
// ---------------------------------------------------------------------------
__global__ __launch_bounds__(256) void vtrans_kernel(const u16* __restrict__ v,
                                                     u16* __restrict__ vt) {
    __shared__ __align__(16) u16 L[128 * 66];
    const int tid = threadIdx.x;
    const int kb = blockIdx.x * 64;
    const int bh = blockIdx.y;
    const u16* vp = v + (size_t)bh * 2048 * 128;
    u16* op = vt + (size_t)bh * 128 * 2048;
#pragma unroll
    for (int i = 0; i < 4; ++i) {
        int c = i * 256 + tid;
        int t = c >> 4, d8 = (c & 15) << 3;
        uint4 x = *(const uint4*)&vp[(kb + t) * 128 + d8];
        const u16* xs = (const u16*)&x;
#pragma unroll
        for (int j = 0; j < 8; ++j) L[(d8 + j) * 66 + t] = xs[j];
    }
    __syncthreads();
#pragma unroll
    for (int i = 0; i < 4; ++i) {
        int c = i * 256 + tid;
        int d = c >> 3, t8 = (c & 7) << 3;
        uint4 x;
        u16* xs = (u16*)&x;
#pragma unroll
        for (int j = 0; j < 8; ++j) xs[j] = L[d * 66 + t8 + j];
        *(uint4*)&op[(size_t)d * 2048 + kb + t8] = x;
    }
}

// ---------------------------------------------------------------------------
// Flash attention (causal), 512 threads = 8 waves, FULL 128-row Q-tile.
// (Unchanged from R13 — validated.)
// ---------------------------------------------------------------------------
__global__ __launch_bounds__(512, 2) void attn_kernel(const u16* __restrict__ q,
                                                      const u16* __restrict__ k,
                                                      const u16* __restrict__ vt,
                                                      u16* __restrict__ ctx) {
    __shared__ __align__(16) u16 Ks[2][64 * 128];   // K [token][d], src-swz
    __shared__ __align__(16) u16 Vs[2][128 * 64];   // V^T [d][token], src-swz
    __shared__ __align__(16) u16 Ps[8][16 * 64];    // per-wave P, swizzled

    const int tid = threadIdx.x;
    const int lane = tid & 63;
    const int wave = tid >> 6;
    const int quad = lane >> 4;
    const int m16 = lane & 15;

    const int l = blockIdx.x;
    const int qt0 = l & 7;
    const int bh = l >> 3;
    const int b = bh >> 4, h = bh & 15;
    const u16* qp = q + (size_t)bh * 2048 * 128;
    const u16* kp = k + (size_t)bh * 2048 * 128;
    const u16* vp = vt + (size_t)bh * 128 * 2048;
    const float scale = 0.08838834764831845f;  // 1/sqrt(128)
    const fx4 zero4 = {0.f, 0.f, 0.f, 0.f};

    // staging geometry: 2 K-slots + 2 V-slots per thread per tile.
    int ksrc[2], vsrc[2];
#pragma unroll
    for (int i = 0; i < 2; ++i) {
        int s = tid + i * 512;
        int r = s >> 4, p = s & 15;
        ksrc[i] = r * 128 + (p ^ (r & 7)) * 8;
        int d = s >> 3, pv = s & 7;
        vsrc[i] = d * 2048 + (pv ^ (d & 7)) * 8;
    }

#define GLD_TILE(kb_, buf_)                                                   \
    {                                                                         \
        _Pragma("unroll") for (int ii = 0; ii < 2; ++ii) {                    \
            gld16(kp + (size_t)(kb_)*128 + ksrc[ii],                          \
                  &Ks[buf_][tid * 8 + ii * 4096]);                            \
            gld16(vp + (kb_) + vsrc[ii], &Vs[buf_][tid * 8 + ii * 4096]);     \
        }                                                                     \
    }

#pragma unroll 1
    for (int pass = 0; pass < 2; ++pass) {
        const int qt = pass ? (15 - qt0) : qt0;
        const int qrow0 = qt * 128 + wave * 16;  // wave's 16 rows
        const int nkt = 2 * qt + 2;

        // Q fragment (A-layout: row=m16, k=c*32+quad*8+j)
        bf16x8 qf[4];
#pragma unroll
        for (int c = 0; c < 4; ++c)
            qf[c] = *(const bf16x8*)&qp[(size_t)(qrow0 + m16) * 128 + c * 32 +
                                        quad * 8];

        fx4 o[8];
#pragma unroll
        for (int dn = 0; dn < 8; ++dn) o[dn] = zero4;
        float mi[4], li[4];
#pragma unroll
        for (int r = 0; r < 4; ++r) {
            mi[r] = -1e30f;
            li[r] = 0.f;
        }

        GLD_TILE(0, 0);
        __syncthreads();  // tile 0 resident
        int cur = 0;
        for (int kt = 0; kt < nkt; ++kt) {
            const int kb = kt * 64;
            // prefetch tile kt+1 into the idle buffer (flies under compute)
            if (kt + 1 < nkt) GLD_TILE(kb + 64, cur ^ 1);

            // QK^T: 16 rows x 64 cols
            fx4 sc[4];
#pragma unroll
            for (int nt = 0; nt < 4; ++nt) sc[nt] = zero4;
            __builtin_amdgcn_s_setprio(1);
#pragma unroll
            for (int c = 0; c < 4; ++c)
#pragma unroll
                for (int nt = 0; nt < 4; ++nt) {
                    int e = (nt * 16 + m16) * 128 + c * 32 + quad * 8;
                    bf16x8 kf =
                        *(const bf16x8*)&Ks[cur][e ^ ((m16 & 7) << 3)];
                    sc[nt] = MFMA16(qf[c], kf, sc[nt]);
                }
            __builtin_amdgcn_s_setprio(0);

            // shuffle online softmax (row = quad*4+r, its 16 cols on lanes
            // quad*16..quad*16+15; xor 1/2/4/8 stays inside the group)
#pragma unroll
            for (int r = 0; r < 4; ++r) {
                int rg = qrow0 + quad * 4 + r;
                float mx = mi[r];
#pragma unroll
                for (int nt = 0; nt < 4; ++nt) {
                    int cg = kb + nt * 16 + m16;
                    float s = sc[nt][r] * scale;
                    s = (cg <= rg) ? s : -1e30f;
                    sc[nt][r] = s;
                    mx = fmaxf(mx, s);
                }
                mx = fmaxf(mx, __shfl_xor(mx, 1));
                mx = fmaxf(mx, __shfl_xor(mx, 2));
                mx = fmaxf(mx, __shfl_xor(mx, 4));
                mx = fmaxf(mx, __shfl_xor(mx, 8));
                float alpha = __expf(mi[r] - mx);
                mi[r] = mx;
                float rsum = 0.f;
                int row = quad * 4 + r;
#pragma unroll
                for (int nt = 0; nt < 4; ++nt) {
                    float p = __expf(sc[nt][r] - mx);
                    Ps[wave][(row * 64 + nt * 16 + m16) ^ ((row & 7) << 3)] =
                        f2bf(p);
                    rsum += p;
                }
                rsum += __shfl_xor(rsum, 1);
                rsum += __shfl_xor(rsum, 2);
                rsum += __shfl_xor(rsum, 4);
                rsum += __shfl_xor(rsum, 8);
                li[r] = li[r] * alpha + rsum;
#pragma unroll
                for (int dn = 0; dn < 8; ++dn) o[dn][r] *= alpha;
            }

            // O += P * V. Ps wave-private: same-wave ds ordering suffices.
            __builtin_amdgcn_s_setprio(1);
#pragma unroll
            for (int c2 = 0; c2 < 2; ++c2) {
                bf16x8 pf = *(const bf16x8*)&Ps[wave][(m16 * 64 + c2 * 32 +
                                                       quad * 8) ^
                                                      ((m16 & 7) << 3)];
#pragma unroll
                for (int dn = 0; dn < 8; ++dn) {
                    int e = (dn * 16 + m16) * 64 + c2 * 32 + quad * 8;
                    bf16x8 vf =
                        *(const bf16x8*)&Vs[cur][e ^ ((m16 & 7) << 3)];
                    o[dn] = MFMA16(pf, vf, o[dn]);
                }
            }
            __builtin_amdgcn_s_setprio(0);

            __syncthreads();  // drains prefetch; ends reads of buf cur
            cur ^= 1;
        }

        // epilogue for this pass's 16 rows
#pragma unroll
        for (int r = 0; r < 4; ++r) {
            int row = qrow0 + quad * 4 + r;
            float inv = 1.0f / li[r];
#pragma unroll
            for (int dn = 0; dn < 8; ++dn) {
                int d = dn * 16 + m16;
                ctx[((size_t)(b * 2048 + row)) * 2048 + h * 128 + d] =
                    f2bf(o[dn][r] * inv);
            }
        }
    }
}

// ---------------------------------------------------------------------------
// ws (64 MiB u16): xb 8388608 | wqkvb 12582912 | v/ctx 8388608 | outwb 4194304
// d_out (32 MiB used as scratch until final GEMM): q 8388608 | k 8388608
// vt reuses xb after the QKV GEMM. Final GEMM overwrites d_out (q,k dead).
// ---------------------------------------------------------------------------
extern "C" void kernel_launch(void* const* d_in, const int* in_sizes, int n_in,
                              void* d_out, int out_size, void* d_ws,
                              size_t ws_size, hipStream_t stream) {
    const float* x = (const float*)d_in[0];
    const float* wqkv_w = (const float*)d_in[1];
    const float* wqkv_b = (const float*)d_in[2];
    const float* out_w = (const float*)d_in[3];
    const float* out_b = (const float*)d_in[4];
    u16* ws = (u16*)d_ws;

    u16* xb = ws;                   // 8388608 u16 (later: vt)
    u16* wqkvb = ws + 8388608;      // 12582912 u16
    u16* vb = ws + 20971520;        // 8388608 u16 (later: ctx)
    u16* outwb = ws + 29360128;     // 4194304 u16
    u16* vtb = xb;
    u16* ctx = vb;
    u16* qb = (u16*)d_out;          // 8388608 u16
    u16* kb = qb + 8388608;         // 8388608 u16

    cvt_kernel<<<12288, 256, 0, stream>>>(x, wqkv_w, out_w, xb, wqkvb, outwb);
    gemm_qkv<<<768, 512, 0, stream>>>(xb, wqkvb, wqkv_b, qb, kb, vb);
    rope_kernel<<<16384, 256, 0, stream>>>(qb, kb);
    vtrans_kernel<<<dim3(32, 32), 256, 0, stream>>>(vb, vtb);
    attn_kernel<<<256, 512, 0, stream>>>(qb, kb, vtb, ctx);
    gemm_bt<0><<<dim3(16, 32), 256, 0, stream>>>(ctx, outwb, out_b,
                                                 (float*)d_out, nullptr,
                                                 nullptr, nullptr, 2048, 2048);
}

// Round 17
// 403.826 us; speedup vs baseline: 1.0634x; 1.0379x over previous
//
#include <hip/hip_runtime.h>

typedef unsigned short u16;
typedef unsigned int u32;
typedef __bf16 bf16x8 __attribute__((ext_vector_type(8)));
typedef float fx4 __attribute__((ext_vector_type(4)));

__device__ __forceinline__ float bf2f(u16 u) {
    return __uint_as_float(((u32)u) << 16);
}
__device__ __forceinline__ u16 f2bf(float f) {
    u32 x = __float_as_uint(f);
    u32 r = (x + 0x7fffu + ((x >> 16) & 1u)) >> 16;
    return (u16)r;
}

// async global->LDS, 16B per lane (gfx950). LDS dest must be linear:
// wave-uniform base + lane*16 (we pass per-lane ptrs equal to that).
__device__ __forceinline__ void gld16(const u16* g, u16* l) {
    __builtin_amdgcn_global_load_lds(
        (const __attribute__((address_space(1))) void*)g,
        (__attribute__((address_space(3))) void*)l, 16, 0, 0);
}

#define MFMA16(a, b, c) __builtin_amdgcn_mfma_f32_16x16x32_bf16((a), (b), (c), 0, 0, 0)

// ---------------------------------------------------------------------------
// fp32 -> bf16 bulk convert: x (8388608) | wqkv_w (12582912) | out_w (4194304)
// ---------------------------------------------------------------------------
__global__ __launch_bounds__(256) void cvt_kernel(const float* __restrict__ x,
                                                  const float* __restrict__ w1,
                                                  const float* __restrict__ w2,
                                                  u16* __restrict__ xb,
                                                  u16* __restrict__ w1b,
                                                  u16* __restrict__ w2b) {
    size_t g = ((size_t)blockIdx.x * 256 + threadIdx.x) * 8;
    const float* src;
    u16* dst;
    if (g < 8388608) {
        src = x;
        dst = xb;
    } else if (g < 20971520) {
        src = w1 - 8388608;
        dst = w1b - 8388608;
    } else {
        src = w2 - 20971520;
        dst = w2b - 20971520;
    }
    float4 a = *(const float4*)&src[g];
    float4 b = *(const float4*)&src[g + 4];
    u16 v[8];
    v[0] = f2bf(a.x);
    v[1] = f2bf(a.y);
    v[2] = f2bf(a.z);
    v[3] = f2bf(a.w);
    v[4] = f2bf(b.x);
    v[5] = f2bf(b.y);
    v[6] = f2bf(b.z);
    v[7] = f2bf(b.w);
    *(uint4*)&dst[g] = *(const uint4*)v;
}

// ---------------------------------------------------------------------------
// Phase-pipelined GEMM (T3+T4, verified R15/R16): C = A * B^T (+bias).
// BM=256 x BN=128, BK=64, 512 thr = 8 waves, per-wave output 64x64.
// K fixed 2048 (32 K-tiles), 2 phases per tile (k-halves of 32).
// Per phase: 8 ds_read_b128 -> issue 3 gld16 (t+1, same half, buf^1)
//   -> lgkmcnt(0)+sched_barrier -> setprio(1) 16 MFMA setprio(0)
//   -> s_waitcnt vmcnt(3) -> s_barrier.  vmcnt never 0 in the loop.
// Swizzle (R16, measured 0 conflicts): slot s -> row s>>2, phys unit s&3
// holds global unit (s&3)^((row>>1)&3); reads XOR the same involution.
// LDS 96 KiB -> 1 block/CU.
// MODE 1: qkv scatter (bf16) to qb/kb/vb, N=6144, grid 768 (16x48).
// MODE 0: fp32 C[M][N]+bias,              N=2048, grid 256 (16x16, 1 round).
// ---------------------------------------------------------------------------
template <int MODE>
__global__ __launch_bounds__(512, 2) void gemm_ph(const u16* __restrict__ A,
                                                  const u16* __restrict__ B,
                                                  const float* __restrict__ bias,
                                                  float* __restrict__ Cf,
                                                  u16* __restrict__ qb,
                                                  u16* __restrict__ kb,
                                                  u16* __restrict__ vb,
                                                  int N) {
    const int K = 2048;
    __shared__ __align__(16) u16 As[2][2][256 * 32];
    __shared__ __align__(16) u16 Bs[2][2][128 * 32];

    const int tid = threadIdx.x;
    const int lane = tid & 63;
    const int wave = tid >> 6;
    const int quad = lane >> 4;
    const int m16 = lane & 15;
    const int wm = wave >> 1;  // 0..3
    const int wn = wave & 1;   // 0..1

    const int nblk = N >> 7;
    const int bm = (blockIdx.x / nblk) * 256;
    const int bn = (blockIdx.x % nblk) * 128;
    const u16* Ab = A + (size_t)bm * K;
    const u16* Bbp = B + (size_t)bn * K;

    // staging: A half = 256x32 = 1024 slots (thread: tid, tid+512);
    //          B half = 128x32 = 512 slots (thread: tid).
    const int arow0 = tid >> 2, au0 = (tid & 3) ^ ((arow0 >> 1) & 3);
    const int arow1 = (tid + 512) >> 2, au1 = ((tid + 512) & 3) ^ ((arow1 >> 1) & 3);
    const int brow = tid >> 2, bu = (tid & 3) ^ ((brow >> 1) & 3);

#define QISSUE(t_, h_, buf_)                                                  \
    {                                                                         \
        const int ko_ = (t_)*64 + (h_)*32;                                    \
        gld16(Ab + (size_t)arow0 * K + ko_ + au0 * 8,                         \
              &As[buf_][h_][tid * 8]);                                        \
        gld16(Ab + (size_t)arow1 * K + ko_ + au1 * 8,                         \
              &As[buf_][h_][(tid + 512) * 8]);                                \
        gld16(Bbp + (size_t)brow * K + ko_ + bu * 8,                          \
              &Bs[buf_][h_][tid * 8]);                                        \
    }

    const fx4 zero4 = {0.f, 0.f, 0.f, 0.f};
    fx4 acc[4][4];
#pragma unroll
    for (int i = 0; i < 4; ++i)
#pragma unroll
        for (int j = 0; j < 4; ++j) acc[i][j] = zero4;

#define QPHASE(t_, h_, b_)                                                    \
    {                                                                         \
        bf16x8 af[4], bfr[4];                                                 \
        _Pragma("unroll") for (int mt = 0; mt < 4; ++mt) {                    \
            int row = wm * 64 + mt * 16 + m16;                                \
            af[mt] = *(const bf16x8*)&As[b_][h_]                              \
                         [row * 32 + ((quad ^ ((row >> 1) & 3)) << 3)];       \
        }                                                                     \
        _Pragma("unroll") for (int nt = 0; nt < 4; ++nt) {                    \
            int rc = wn * 64 + nt * 16 + m16;                                 \
            bfr[nt] = *(const bf16x8*)&Bs[b_][h_]                             \
                          [rc * 32 + ((quad ^ ((rc >> 1) & 3)) << 3)];        \
        }                                                                     \
        if ((t_) + 1 < 32) QISSUE((t_) + 1, h_, (b_) ^ 1);                    \
        asm volatile("s_waitcnt lgkmcnt(0)" ::: "memory");                    \
        __builtin_amdgcn_sched_barrier(0);                                    \
        __builtin_amdgcn_s_setprio(1);                                        \
        _Pragma("unroll") for (int mt = 0; mt < 4; ++mt)                      \
            _Pragma("unroll") for (int nt = 0; nt < 4; ++nt)                  \
                acc[mt][nt] = MFMA16(af[mt], bfr[nt], acc[mt][nt]);           \
        __builtin_amdgcn_s_setprio(0);                                       \
        __builtin_amdgcn_sched_barrier(0);                                    \
        asm volatile("s_waitcnt vmcnt(3)" ::: "memory");                      \
        __builtin_amdgcn_s_barrier();                                         \
    }

    // prologue: stage tile 0 (both halves); k0 resident, k1 in flight.
    QISSUE(0, 0, 0);
    QISSUE(0, 1, 0);
    asm volatile("s_waitcnt vmcnt(3)" ::: "memory");
    __builtin_amdgcn_s_barrier();

    for (int t = 0; t < 32; ++t) {
        const int b = t & 1;
        QPHASE(t, 0, b);
        QPHASE(t, 1, b);
    }

    // epilogue
#pragma unroll
    for (int mt = 0; mt < 4; ++mt) {
#pragma unroll
        for (int rr = 0; rr < 4; ++rr) {
            int row = bm + wm * 64 + mt * 16 + quad * 4 + rr;
#pragma unroll
            for (int nt = 0; nt < 4; ++nt) {
                int col = bn + wn * 64 + nt * 16 + m16;
                float v = acc[mt][nt][rr] + bias[col];
                if (MODE == 0) {
                    Cf[(size_t)row * N + col] = v;
                } else {
                    int which = col >> 11;
                    int h = (col >> 7) & 15;
                    int d = col & 127;
                    int b2 = row >> 11;
                    int s = row & 2047;
                    u16* dst = (which == 0) ? qb : ((which == 1) ? kb : vb);
                    dst[(size_t)((b2 * 16 + h) * 2048 + s) * 128 + d] = f2bf(v);
                }
            }
        }
    }
#undef QPHASE
#undef QISSUE
}

// ---------------------------------------------------------------------------
// RoPE in place on q and k (bf16), layout [bh][s][128]; pair (i, i+64).
// ---------------------------------------------------------------------------
__global__ __launch_bounds__(256) void rope_kernel(u16* __restrict__ q,
                                                   u16* __restrict__ k) {
    int t = blockIdx.x * 256 + threadIdx.x;
    int i = t & 63;
    int s = (t >> 6) & 2047;
    int bh = t >> 17;
    float inv = exp2f(-(float)i * 0.2076205059304595f);  // 10000^(-i/64)
    float ang = (float)s * inv;
    float sn, cs;
    sincosf(ang, &sn, &cs);
    size_t base = ((size_t)bh * 2048 + s) * 128 + i;
    {
        float x1 = bf2f(q[base]), x2 = bf2f(q[base + 64]);
        q[base] = f2bf(x1 * cs - x2 * sn);
        q[base + 64] = f2bf(x1 * sn + x2 * cs);
    }
    {
        float x1 = bf2f(k[base]), x2 = bf2f(k[base + 64]);
        k[base] = f2bf(x1 * cs - x2 * sn);
        k[base + 64] = f2bf(x1 * sn + x2 * cs);
    }
}

// ---------------------------------------------------------------------------
// V transpose: [bh][s][d] -> [bh][d][s] (bf16 ws).
// ---------------------------------------------------------------------------
__global__ __launch_bounds__(256) void vtrans_kernel(const u16* __restrict__ v,
                                                     u16* __restrict__ vt) {
    __shared__ __align__(16) u16 L[128 * 66];
    const int tid = threadIdx.x;
    const int kb = blockIdx.x * 64;
    const int bh = blockIdx.y;
    const u16* vp = v + (size_t)bh * 2048 * 128;
    u16* op = vt + (size_t)bh * 128 * 2048;
#pragma unroll
    for (int i = 0; i < 4; ++i) {
        int c = i * 256 + tid;
        int t = c >> 4, d8 = (c & 15) << 3;
        uint4 x = *(const uint4*)&vp[(kb + t) * 128 + d8];
        const u16* xs = (const u16*)&x;
#pragma unroll
        for (int j = 0; j < 8; ++j) L[(d8 + j) * 66 + t] = xs[j];
    }
    __syncthreads();
#pragma unroll
    for (int i = 0; i < 4; ++i) {
        int c = i * 256 + tid;
        int d = c >> 3, t8 = (c & 7) << 3;
        uint4 x;
        u16* xs = (u16*)&x;
#pragma unroll
        for (int j = 0; j < 8; ++j) xs[j] = L[d * 66 + t8 + j];
        *(uint4*)&op[(size_t)d * 2048 + kb + t8] = x;
    }
}

// ---------------------------------------------------------------------------
// Flash attention (causal), 512 threads = 8 waves, FULL 128-row Q-tile.
// (Unchanged from R13 — validated.)
// ---------------------------------------------------------------------------
__global__ __launch_bounds__(512, 2) void attn_kernel(const u16* __restrict__ q,
                                                      const u16* __restrict__ k,
                                                      const u16* __restrict__ vt,
                                                      u16* __restrict__ ctx) {
    __shared__ __align__(16) u16 Ks[2][64 * 128];   // K [token][d], src-swz
    __shared__ __align__(16) u16 Vs[2][128 * 64];   // V^T [d][token], src-swz
    __shared__ __align__(16) u16 Ps[8][16 * 64];    // per-wave P, swizzled

    const int tid = threadIdx.x;
    const int lane = tid & 63;
    const int wave = tid >> 6;
    const int quad = lane >> 4;
    const int m16 = lane & 15;

    const int l = blockIdx.x;
    const int qt0 = l & 7;
    const int bh = l >> 3;
    const int b = bh >> 4, h = bh & 15;
    const u16* qp = q + (size_t)bh * 2048 * 128;
    const u16* kp = k + (size_t)bh * 2048 * 128;
    const u16* vp = vt + (size_t)bh * 128 * 2048;
    const float scale = 0.08838834764831845f;  // 1/sqrt(128)
    const fx4 zero4 = {0.f, 0.f, 0.f, 0.f};

    // staging geometry: 2 K-slots + 2 V-slots per thread per tile.
    int ksrc[2], vsrc[2];
#pragma unroll
    for (int i = 0; i < 2; ++i) {
        int s = tid + i * 512;
        int r = s >> 4, p = s & 15;
        ksrc[i] = r * 128 + (p ^ (r & 7)) * 8;
        int d = s >> 3, pv = s & 7;
        vsrc[i] = d * 2048 + (pv ^ (d & 7)) * 8;
    }

#define GLD_TILE(kb_, buf_)                                                   \
    {                                                                         \
        _Pragma("unroll") for (int ii = 0; ii < 2; ++ii) {                    \
            gld16(kp + (size_t)(kb_)*128 + ksrc[ii],                          \
                  &Ks[buf_][tid * 8 + ii * 4096]);                            \
            gld16(vp + (kb_) + vsrc[ii], &Vs[buf_][tid * 8 + ii * 4096]);     \
        }                                                                     \
    }

#pragma unroll 1
    for (int pass = 0; pass < 2; ++pass) {
        const int qt = pass ? (15 - qt0) : qt0;
        const int qrow0 = qt * 128 + wave * 16;  // wave's 16 rows
        const int nkt = 2 * qt + 2;

        // Q fragment (A-layout: row=m16, k=c*32+quad*8+j)
        bf16x8 qf[4];
#pragma unroll
        for (int c = 0; c < 4; ++c)
            qf[c] = *(const bf16x8*)&qp[(size_t)(qrow0 + m16) * 128 + c * 32 +
                                        quad * 8];

        fx4 o[8];
#pragma unroll
        for (int dn = 0; dn < 8; ++dn) o[dn] = zero4;
        float mi[4], li[4];
#pragma unroll
        for (int r = 0; r < 4; ++r) {
            mi[r] = -1e30f;
            li[r] = 0.f;
        }

        GLD_TILE(0, 0);
        __syncthreads();  // tile 0 resident
        int cur = 0;
        for (int kt = 0; kt < nkt; ++kt) {
            const int kb = kt * 64;
            // prefetch tile kt+1 into the idle buffer (flies under compute)
            if (kt + 1 < nkt) GLD_TILE(kb + 64, cur ^ 1);

            // QK^T: 16 rows x 64 cols
            fx4 sc[4];
#pragma unroll
            for (int nt = 0; nt < 4; ++nt) sc[nt] = zero4;
            __builtin_amdgcn_s_setprio(1);
#pragma unroll
            for (int c = 0; c < 4; ++c)
#pragma unroll
                for (int nt = 0; nt < 4; ++nt) {
                    int e = (nt * 16 + m16) * 128 + c * 32 + quad * 8;
                    bf16x8 kf =
                        *(const bf16x8*)&Ks[cur][e ^ ((m16 & 7) << 3)];
                    sc[nt] = MFMA16(qf[c], kf, sc[nt]);
                }
            __builtin_amdgcn_s_setprio(0);

            // shuffle online softmax (row = quad*4+r, its 16 cols on lanes
            // quad*16..quad*16+15; xor 1/2/4/8 stays inside the group)
#pragma unroll
            for (int r = 0; r < 4; ++r) {
                int rg = qrow0 + quad * 4 + r;
                float mx = mi[r];
#pragma unroll
                for (int nt = 0; nt < 4; ++nt) {
                    int cg = kb + nt * 16 + m16;
                    float s = sc[nt][r] * scale;
                    s = (cg <= rg) ? s : -1e30f;
                    sc[nt][r] = s;
                    mx = fmaxf(mx, s);
                }
                mx = fmaxf(mx, __shfl_xor(mx, 1));
                mx = fmaxf(mx, __shfl_xor(mx, 2));
                mx = fmaxf(mx, __shfl_xor(mx, 4));
                mx = fmaxf(mx, __shfl_xor(mx, 8));
                float alpha = __expf(mi[r] - mx);
                mi[r] = mx;
                float rsum = 0.f;
                int row = quad * 4 + r;
#pragma unroll
                for (int nt = 0; nt < 4; ++nt) {
                    float p = __expf(sc[nt][r] - mx);
                    Ps[wave][(row * 64 + nt * 16 + m16) ^ ((row & 7) << 3)] =
                        f2bf(p);
                    rsum += p;
                }
                rsum += __shfl_xor(rsum, 1);
                rsum += __shfl_xor(rsum, 2);
                rsum += __shfl_xor(rsum, 4);
                rsum += __shfl_xor(rsum, 8);
                li[r] = li[r] * alpha + rsum;
#pragma unroll
                for (int dn = 0; dn < 8; ++dn) o[dn][r] *= alpha;
            }

            // O += P * V. Ps wave-private: same-wave ds ordering suffices.
            __builtin_amdgcn_s_setprio(1);
#pragma unroll
            for (int c2 = 0; c2 < 2; ++c2) {
                bf16x8 pf = *(const bf16x8*)&Ps[wave][(m16 * 64 + c2 * 32 +
                                                       quad * 8) ^
                                                      ((m16 & 7) << 3)];
#pragma unroll
                for (int dn = 0; dn < 8; ++dn) {
                    int e = (dn * 16 + m16) * 64 + c2 * 32 + quad * 8;
                    bf16x8 vf =
                        *(const bf16x8*)&Vs[cur][e ^ ((m16 & 7) << 3)];
                    o[dn] = MFMA16(pf, vf, o[dn]);
                }
            }
            __builtin_amdgcn_s_setprio(0);

            __syncthreads();  // drains prefetch; ends reads of buf cur
            cur ^= 1;
        }

        // epilogue for this pass's 16 rows
#pragma unroll
        for (int r = 0; r < 4; ++r) {
            int row = qrow0 + quad * 4 + r;
            float inv = 1.0f / li[r];
#pragma unroll
            for (int dn = 0; dn < 8; ++dn) {
                int d = dn * 16 + m16;
                ctx[((size_t)(b * 2048 + row)) * 2048 + h * 128 + d] =
                    f2bf(o[dn][r] * inv);
            }
        }
    }
}

// ---------------------------------------------------------------------------
// ws (64 MiB u16): xb 8388608 | wqkvb 12582912 | v/ctx 8388608 | outwb 4194304
// d_out (32 MiB used as scratch until final GEMM): q 8388608 | k 8388608
// vt reuses xb after the QKV GEMM. Final GEMM overwrites d_out (q,k dead).
// ---------------------------------------------------------------------------
extern "C" void kernel_launch(void* const* d_in, const int* in_sizes, int n_in,
                              void* d_out, int out_size, void* d_ws,
                              size_t ws_size, hipStream_t stream) {
    const float* x = (const float*)d_in[0];
    const float* wqkv_w = (const float*)d_in[1];
    const float* wqkv_b = (const float*)d_in[2];
    const float* out_w = (const float*)d_in[3];
    const float* out_b = (const float*)d_in[4];
    u16* ws = (u16*)d_ws;

    u16* xb = ws;                   // 8388608 u16 (later: vt)
    u16* wqkvb = ws + 8388608;      // 12582912 u16
    u16* vb = ws + 20971520;        // 8388608 u16 (later: ctx)
    u16* outwb = ws + 29360128;     // 4194304 u16
    u16* vtb = xb;
    u16* ctx = vb;
    u16* qb = (u16*)d_out;          // 8388608 u16
    u16* kb = qb + 8388608;         // 8388608 u16

    cvt_kernel<<<12288, 256, 0, stream>>>(x, wqkv_w, out_w, xb, wqkvb, outwb);
    gemm_ph<1><<<768, 512, 0, stream>>>(xb, wqkvb, wqkv_b, nullptr, qb, kb, vb,
                                        6144);
    rope_kernel<<<16384, 256, 0, stream>>>(qb, kb);
    vtrans_kernel<<<dim3(32, 32), 256, 0, stream>>>(vb, vtb);
    attn_kernel<<<256, 512, 0, stream>>>(qb, kb, vtb, ctx);
    gemm_ph<0><<<256, 512, 0, stream>>>(ctx, outwb, out_b, (float*)d_out,
                                        nullptr, nullptr, nullptr, 2048);
}